// Round 6
// baseline (837.331 us; speedup 1.0000x reference)
//
#include <hip/hip_runtime.h>
#include <math.h>

#define NN 50000
#define NE 600000
#define DD 128
#define NL 4
#define NG 512
#define NT 10
#define EPSF 1e-5f

typedef __bf16 bf16x8 __attribute__((ext_vector_type(8)));
typedef float f32x4 __attribute__((ext_vector_type(4)));

__device__ __forceinline__ unsigned short f2bf(float x) {
    union { float f; unsigned u; } v; v.f = x;
    unsigned r = v.u + 0x7FFFu + ((v.u >> 16) & 1u);
    return (unsigned short)(r >> 16);
}
__device__ __forceinline__ unsigned pack_bf2(float a, float b) {
    return (unsigned)f2bf(a) | ((unsigned)f2bf(b) << 16);
}
__device__ __forceinline__ float bf_lo(unsigned v) {
    union { unsigned u; float f; } w; w.u = (v & 0xFFFFu) << 16; return w.f;
}
__device__ __forceinline__ float bf_hi(unsigned v) {
    union { unsigned u; float f; } w; w.u = v & 0xFFFF0000u; return w.f;
}

// ---------------- CSR build ----------------
__global__ void k_count(const int* __restrict__ dst, int* __restrict__ deg,
                        float* __restrict__ dsum, int E) {
    int e = blockIdx.x * blockDim.x + threadIdx.x;
    if (e == 0) *dsum = 0.f;                 // consumed by k_delta (later kernel)
    if (e < E) atomicAdd(&deg[dst[e]], 1);
}

// parallel scan: 49 blocks x 256 thr, 4 elems/thread (1024/block)
__global__ void k_scan_part(const int* __restrict__ deg, int* __restrict__ part, int n) {
    __shared__ int sm[256];
    int b = blockIdx.x, t = threadIdx.x;
    int base = b * 1024 + t * 4;
    int s = 0;
    #pragma unroll
    for (int j = 0; j < 4; j++) if (base + j < n) s += deg[base + j];
    sm[t] = s;
    __syncthreads();
    for (int off = 128; off > 0; off >>= 1) {
        if (t < off) sm[t] += sm[t + off];
        __syncthreads();
    }
    if (t == 0) part[b] = sm[0];
}

__global__ void k_scan_top(const int* __restrict__ part, int* __restrict__ offs,
                           int* __restrict__ row_ptr, int nb, int n) {
    if (threadIdx.x == 0) {
        int acc = 0;
        for (int i = 0; i < nb; i++) { offs[i] = acc; acc += part[i]; }
        row_ptr[n] = acc;
    }
}

__global__ void k_scan_apply(const int* __restrict__ deg, const int* __restrict__ offs,
                             int* __restrict__ row_ptr, int* __restrict__ cursor, int n) {
    __shared__ int sm[256];
    int b = blockIdx.x, t = threadIdx.x;
    int base = b * 1024 + t * 4;
    int v[4]; int s = 0;
    #pragma unroll
    for (int j = 0; j < 4; j++) { v[j] = (base + j < n) ? deg[base + j] : 0; s += v[j]; }
    sm[t] = s;
    __syncthreads();
    for (int off = 1; off < 256; off <<= 1) {
        int y = (t >= off) ? sm[t - off] : 0;
        __syncthreads();
        sm[t] += y;
        __syncthreads();
    }
    int run = offs[b] + sm[t] - s;
    #pragma unroll
    for (int j = 0; j < 4; j++) {
        if (base + j < n) { row_ptr[base + j] = run; cursor[base + j] = run; run += v[j]; }
    }
}

__global__ void k_fill(const int* __restrict__ src, const int* __restrict__ dst,
                       int* __restrict__ cursor, int* __restrict__ csr_src, int E) {
    int e = blockIdx.x * blockDim.x + threadIdx.x;
    if (e < E) {
        int d = dst[e];
        int pos = atomicAdd(&cursor[d], 1);
        csr_src[pos] = src[e];
    }
}

// ---------------- degree scalars ----------------
__global__ void k_delta(const int* __restrict__ deg, float* __restrict__ dsum, int n) {
    int i = blockIdx.x * blockDim.x + threadIdx.x;
    float v = (i < n) ? log1pf((float)deg[i]) : 0.f;
    #pragma unroll
    for (int off = 32; off > 0; off >>= 1) v += __shfl_down(v, off);
    if ((threadIdx.x & 63) == 0) atomicAdd(dsum, v);
}

__global__ void k_scalars(const int* __restrict__ deg, const float* __restrict__ dsum,
                          float* __restrict__ inv_d, float* __restrict__ amp,
                          float* __restrict__ att, int n) {
    int i = blockIdx.x * blockDim.x + threadIdx.x;
    if (i >= n) return;
    float delta = *dsum / (float)n;
    float d = fmaxf((float)deg[i], 1.f);
    float ld = log1pf(d);
    inv_d[i] = 1.f / d;
    amp[i] = ld / delta;
    att[i] = delta / ld;
}

// ---------------- node embedding (fp32 h + bf16 mirror) ----------------
__global__ void k_emb(const float* __restrict__ x, const float* __restrict__ W,
                      const float* __restrict__ b, float* __restrict__ h,
                      unsigned* __restrict__ hb2, int total2) {
    int i = blockIdx.x * blockDim.x + threadIdx.x;
    if (i >= total2) return;
    int node = i >> 6, c = (i & 63) * 2;
    float x0 = x[node * 3 + 0], x1 = x[node * 3 + 1], x2 = x[node * 3 + 2];
    float v0 = x0 * W[c] + x1 * W[DD + c] + x2 * W[2 * DD + c] + b[c];
    float v1 = x0 * W[c + 1] + x1 * W[DD + c + 1] + x2 * W[2 * DD + c + 1] + b[c + 1];
    ((float2*)h)[i] = make_float2(v0, v1);
    hb2[i] = pack_bf2(v0, v1);
}

// ---------------- weight convert: conv_W [L,1536,128] f32 -> Bt [L][3][128][512] bf16 ----
__global__ void k_wconv(const float* __restrict__ W, unsigned short* __restrict__ Bt, int total) {
    int o = blockIdx.x * blockDim.x + threadIdx.x;
    if (o >= total) return;
    int l = o / 196608;
    int r = o % 196608;
    int j = r >> 16;
    int r2 = r & 65535;
    int n = r2 >> 9;
    int k = r2 & 511;
    Bt[o] = f2bf(W[(size_t)l * 196608 + (size_t)(j * 512 + k) * 128 + n]);
}

// ---------------- PNA aggregation (4 nodes/block, wave per node) ----------------
__global__ void k_agg(const unsigned* __restrict__ hb2, const int* __restrict__ row_ptr,
                      const int* __restrict__ csr_src, const float* __restrict__ inv_d,
                      unsigned* __restrict__ aggs_u, float* __restrict__ bn_zero) {
    int tid = threadIdx.x;
    if (blockIdx.x == 0) bn_zero[tid] = 0.f;   // zero bn_sum[128]+bn_sq[128] for next gemm
    int node = blockIdx.x * 4 + (tid >> 6);
    int t = tid & 63;
    int beg = row_ptr[node], end = row_ptr[node + 1];
    float s1a = 0.f, s1b = 0.f, s2a = 0.f, s2b = 0.f;
    float mna = INFINITY, mnb = INFINITY, mxa = -INFINITY, mxb = -INFINITY;
    int e = beg;
    for (; e + 1 < end; e += 2) {             // x2 unroll: 2 independent loads in flight
        int sa = csr_src[e], sb = csr_src[e + 1];
        unsigned va = hb2[(size_t)sa * 64 + t];
        unsigned vb = hb2[(size_t)sb * 64 + t];
        float a0 = bf_lo(va), b0 = bf_hi(va);
        float a1 = bf_lo(vb), b1 = bf_hi(vb);
        s1a += a0 + a1; s2a += a0 * a0 + a1 * a1;
        mna = fminf(mna, fminf(a0, a1)); mxa = fmaxf(mxa, fmaxf(a0, a1));
        s1b += b0 + b1; s2b += b0 * b0 + b1 * b1;
        mnb = fminf(mnb, fminf(b0, b1)); mxb = fmaxf(mxb, fmaxf(b0, b1));
    }
    if (e < end) {
        int sa = csr_src[e];
        unsigned va = hb2[(size_t)sa * 64 + t];
        float a0 = bf_lo(va), b0 = bf_hi(va);
        s1a += a0; s2a += a0 * a0; mna = fminf(mna, a0); mxa = fmaxf(mxa, a0);
        s1b += b0; s2b += b0 * b0; mnb = fminf(mnb, b0); mxb = fmaxf(mxb, b0);
    }
    float id = inv_d[node];
    float meana = s1a * id, meanb = s1b * id;
    float sda = sqrtf(fmaxf(s2a * id - meana * meana, 0.f) + EPSF);
    float sdb = sqrtf(fmaxf(s2b * id - meanb * meanb, 0.f) + EPSF);
    if (beg == end) { mna = 0.f; mxa = 0.f; mnb = 0.f; mxb = 0.f; }
    unsigned* outr = aggs_u + (size_t)node * 256;
    outr[t]       = pack_bf2(meana, meanb);
    outr[64 + t]  = pack_bf2(mna, mnb);
    outr[128 + t] = pack_bf2(mxa, mxb);
    outr[192 + t] = pack_bf2(sda, sdb);
}

// ---------------- MFMA GEMM v6: LDS-free, direct-fragment loads ----------------
// A = aggs bf16 [N,512]; Bt = [3][128][512] bf16 (n-major, k contiguous).
// out[r,c] = sum_k A[r,k]*(B0 + amp[r]*B1 + att[r]*B2)[k,c] + bias[c]
// 256 thr (4 waves), tile 128 rows x 64 cols; wave (wrow=w>>1, wcol=w&1) owns
// rows [64*wrow,+64) x cols [32*wcol,+32). Each lane loads its MFMA fragments
// straight from global: lane(quad,l16) reads 16B at k0+quad*8 of row/col l16 —
// l16-group spans 64B contiguous => cache-line coalesced. B frags identical
// across blocks (L2-hit); A streams once, reused 4x via L3. NO LDS, NO
// __syncthreads in the K-loop => no vmcnt(0) drains (the rounds-2..5 limiter).
// #pragma unroll 1 prevents whole-loop load hoisting (round-3 spill lesson);
// latency hidden by 3 waves/SIMD TLP (m114).
__global__ __launch_bounds__(256) void k_gemm_mfma(
    const unsigned short* __restrict__ A, const unsigned short* __restrict__ Bt,
    const float* __restrict__ bias, const float* __restrict__ amp,
    const float* __restrict__ att, float* __restrict__ outp,
    float* __restrict__ bn_sum, float* __restrict__ bn_sq, int n) {
    int tid = threadIdx.x;
    int w = tid >> 6, lane = tid & 63;
    int wrow = w >> 1, wcol = w & 1;
    int quad = lane >> 4, l16 = lane & 15;
    int row0 = blockIdx.x * 128;
    int c0 = blockIdx.y * 64;

    f32x4 acc[4][2][3];
    #pragma unroll
    for (int rt = 0; rt < 4; rt++)
        #pragma unroll
        for (int ct = 0; ct < 2; ct++)
            #pragma unroll
            for (int j = 0; j < 3; j++) acc[rt][ct][j] = (f32x4)(0.f);

    const unsigned short* pA[4];
    #pragma unroll
    for (int rt = 0; rt < 4; rt++)
        pA[rt] = A + (size_t)(row0 + wrow * 64 + rt * 16 + l16) * 512 + quad * 8;
    const unsigned short* pB[2][3];
    #pragma unroll
    for (int ct = 0; ct < 2; ct++)
        #pragma unroll
        for (int j = 0; j < 3; j++)
            pB[ct][j] = Bt + (size_t)(j * 128 + c0 + wcol * 32 + ct * 16 + l16) * 512 + quad * 8;

    #pragma unroll 1
    for (int k0 = 0; k0 < 512; k0 += 32) {
        bf16x8 af[4];
        #pragma unroll
        for (int rt = 0; rt < 4; rt++) af[rt] = *(const bf16x8*)(pA[rt] + k0);
        bf16x8 bfr[2][3];
        #pragma unroll
        for (int ct = 0; ct < 2; ct++)
            #pragma unroll
            for (int j = 0; j < 3; j++) bfr[ct][j] = *(const bf16x8*)(pB[ct][j] + k0);
        #pragma unroll
        for (int ct = 0; ct < 2; ct++)
            #pragma unroll
            for (int j = 0; j < 3; j++)
                #pragma unroll
                for (int rt = 0; rt < 4; rt++)
                    acc[rt][ct][j] = __builtin_amdgcn_mfma_f32_16x16x32_bf16(
                        af[rt], bfr[ct][j], acc[rt][ct][j], 0, 0, 0);
    }

    // epilogue: combine j via amp/att, bias, write, BN partials
    float psum[2] = {0.f, 0.f}, psq[2] = {0.f, 0.f};
    #pragma unroll
    for (int rt = 0; rt < 4; rt++) {
        #pragma unroll
        for (int reg = 0; reg < 4; reg++) {
            int row = row0 + wrow * 64 + rt * 16 + quad * 4 + reg;
            if (row < n) {
                float am = amp[row], at = att[row];
                #pragma unroll
                for (int ct = 0; ct < 2; ct++) {
                    int col = c0 + wcol * 32 + ct * 16 + l16;
                    float v = acc[rt][ct][0][reg] + am * acc[rt][ct][1][reg]
                            + at * acc[rt][ct][2][reg] + bias[col];
                    outp[(size_t)row * DD + col] = v;
                    psum[ct] += v;
                    psq[ct] += v * v;
                }
            }
        }
    }
    #pragma unroll
    for (int ct = 0; ct < 2; ct++) {
        psum[ct] += __shfl_xor(psum[ct], 16, 64);
        psum[ct] += __shfl_xor(psum[ct], 32, 64);
        psq[ct]  += __shfl_xor(psq[ct], 16, 64);
        psq[ct]  += __shfl_xor(psq[ct], 32, 64);
    }
    if (quad == 0) {
        #pragma unroll
        for (int ct = 0; ct < 2; ct++) {
            int col = c0 + wcol * 32 + ct * 16 + l16;
            atomicAdd(&bn_sum[col], psum[ct]);
            atomicAdd(&bn_sq[col], psq[ct]);
        }
    }
}

// ---------------- BN stats+apply+relu+residual (fused; updates h fp32 + bf16 mirror) ----
__global__ void k_bnapply(const float* __restrict__ outp, const float* __restrict__ bn_sum,
                          const float* __restrict__ bn_sq, const float* __restrict__ gamma,
                          const float* __restrict__ beta, float* __restrict__ h,
                          unsigned* __restrict__ hb2, int total4) {
    int i = blockIdx.x * blockDim.x + threadIdx.x;
    if (i >= total4) return;
    int c = (i & 31) * 4;
    const float invn = 1.f / (float)NN;
    float4 o = ((const float4*)outp)[i];
    float4 hh = ((float4*)h)[i];
    float oo[4] = {o.x, o.y, o.z, o.w};
    float hs[4] = {hh.x, hh.y, hh.z, hh.w};
    #pragma unroll
    for (int j = 0; j < 4; j++) {
        float mu = bn_sum[c + j] * invn;
        float var = bn_sq[c + j] * invn - mu * mu;
        float sc = rsqrtf(var + EPSF) * gamma[c + j];
        float sh = beta[c + j] - mu * sc;
        hs[j] += fmaxf(oo[j] * sc + sh, 0.f);
    }
    ((float4*)h)[i] = make_float4(hs[0], hs[1], hs[2], hs[3]);
    hb2[i * 2]     = pack_bf2(hs[0], hs[1]);
    hb2[i * 2 + 1] = pack_bf2(hs[2], hs[3]);
}

// ---------------- pool + MLP ----------------
__global__ void k_pool_mlp(const float* __restrict__ h, const int* __restrict__ batch,
                           const float* __restrict__ W1, const float* __restrict__ b1,
                           const float* __restrict__ W2, const float* __restrict__ b2,
                           const float* __restrict__ W3, const float* __restrict__ b3,
                           float* __restrict__ out, int n) {
    __shared__ float gvec[128];
    __shared__ float h1[64];
    __shared__ float h2[32];
    __shared__ int srange[2];
    int g = blockIdx.x;
    int t = threadIdx.x;
    if (t < 2) {
        int target = g + t;
        int lo = 0, hi = n;
        while (lo < hi) {
            int mid = (lo + hi) >> 1;
            if (batch[mid] < target) lo = mid + 1; else hi = mid;
        }
        srange[t] = lo;
    }
    __syncthreads();
    int s = srange[0], e = srange[1];
    float acc = 0.f;
    for (int i = s; i < e; i++) acc += h[(size_t)i * DD + t];
    float cnt = fmaxf((float)(e - s), 1.f);
    gvec[t] = acc / cnt;
    __syncthreads();
    if (t < 64) {
        float a = b1[t];
        for (int k = 0; k < 128; k++) a += gvec[k] * W1[k * 64 + t];
        h1[t] = fmaxf(a, 0.f);
    }
    __syncthreads();
    if (t < 32) {
        float a = b2[t];
        for (int k = 0; k < 64; k++) a += h1[k] * W2[k * 32 + t];
        h2[t] = fmaxf(a, 0.f);
    }
    __syncthreads();
    if (t < 10) {
        float a = b3[t];
        for (int k = 0; k < 32; k++) a += h2[k] * W3[k * 10 + t];
        out[g * NT + t] = a;
    }
}

extern "C" void kernel_launch(void* const* d_in, const int* in_sizes, int n_in,
                              void* d_out, int out_size, void* d_ws, size_t ws_size,
                              hipStream_t stream) {
    const float* x      = (const float*)d_in[0];
    const int*   eidx   = (const int*)d_in[1];
    const int*   batch  = (const int*)d_in[2];
    const float* emb_W  = (const float*)d_in[3];
    const float* emb_b  = (const float*)d_in[4];
    const float* conv_W = (const float*)d_in[5];
    const float* conv_b = (const float*)d_in[6];
    const float* bn_g   = (const float*)d_in[7];
    const float* bn_b   = (const float*)d_in[8];
    const float* W1 = (const float*)d_in[9];
    const float* b1 = (const float*)d_in[10];
    const float* W2 = (const float*)d_in[11];
    const float* b2 = (const float*)d_in[12];
    const float* W3 = (const float*)d_in[13];
    const float* b3 = (const float*)d_in[14];
    float* out = (float*)d_out;

    const int* src = eidx;
    const int* dst = eidx + NE;

    char* p = (char*)d_ws;
    auto carve = [&](size_t bytes) {
        void* r = (void*)p;
        p += (bytes + 255) & ~(size_t)255;
        return r;
    };
    int* deg      = (int*)carve(NN * 4);
    int* row_ptr  = (int*)carve((NN + 1) * 4);
    int* cursor   = (int*)carve(NN * 4);
    int* csr_src  = (int*)carve(NE * 4);
    int* part     = (int*)carve(64 * 4);
    int* offs     = (int*)carve(64 * 4);
    float* inv_d  = (float*)carve(NN * 4);
    float* amp    = (float*)carve(NN * 4);
    float* att    = (float*)carve(NN * 4);
    float* dsum   = (float*)carve(4);
    float* bn_sum = (float*)carve(DD * 4);
    float* bn_sq  = (float*)carve(DD * 4);
    float* h      = (float*)carve((size_t)NN * DD * 4);
    unsigned* hb2 = (unsigned*)carve((size_t)NN * 64 * 4);
    unsigned* aggs_u = (unsigned*)carve((size_t)NN * 256 * 4);   // bf16 [N,512]
    float* outp   = (float*)carve((size_t)NN * DD * 4);          // must follow aggs (OOB pad)
    unsigned short* Bt = (unsigned short*)carve((size_t)NL * 3 * 128 * 512 * 2);

    hipMemsetAsync(deg, 0, NN * 4, stream);

    const int NSB = (NN + 1023) / 1024;   // 49 scan blocks
    k_count<<<(NE + 255) / 256, 256, 0, stream>>>(dst, deg, dsum, NE);
    k_scan_part<<<NSB, 256, 0, stream>>>(deg, part, NN);
    k_scan_top<<<1, 64, 0, stream>>>(part, offs, row_ptr, NSB, NN);
    k_scan_apply<<<NSB, 256, 0, stream>>>(deg, offs, row_ptr, cursor, NN);
    k_fill<<<(NE + 255) / 256, 256, 0, stream>>>(src, dst, cursor, csr_src, NE);
    k_delta<<<(NN + 255) / 256, 256, 0, stream>>>(deg, dsum, NN);
    k_scalars<<<(NN + 255) / 256, 256, 0, stream>>>(deg, dsum, inv_d, amp, att, NN);
    k_emb<<<(NN * 64 + 255) / 256, 256, 0, stream>>>(x, emb_W, emb_b, h, hb2, NN * 64);
    k_wconv<<<(NL * 196608 + 255) / 256, 256, 0, stream>>>(conv_W, Bt, NL * 196608);

    dim3 gemm_grid((NN + 127) / 128, 2);   // 391 x 2 = 782 blocks
    for (int l = 0; l < NL; l++) {
        k_agg<<<(NN + 3) / 4, 256, 0, stream>>>(hb2, row_ptr, csr_src, inv_d, aggs_u, bn_sum);
        k_gemm_mfma<<<gemm_grid, 256, 0, stream>>>(
            (const unsigned short*)aggs_u, Bt + (size_t)l * 3 * 128 * 512,
            conv_b + l * DD, amp, att, outp, bn_sum, bn_sq, NN);
        k_bnapply<<<(NN * 32 + 255) / 256, 256, 0, stream>>>(
            outp, bn_sum, bn_sq, bn_g + l * DD, bn_b + l * DD, h, hb2, NN * 32);
    }

    k_pool_mlp<<<NG, 128, 0, stream>>>(h, batch, W1, b1, W2, b2, W3, b3, out, NN);
}

// Round 7
// 690.206 us; speedup vs baseline: 1.2132x; 1.2132x over previous
//
#include <hip/hip_runtime.h>
#include <math.h>

#define NN 50000
#define NE 600000
#define DD 128
#define NL 4
#define NG 512
#define NT 10
#define NPAD 50176          // 196 * 256, padded row count for A_t
#define EPSF 1e-5f

typedef __bf16 bf16x8 __attribute__((ext_vector_type(8)));
typedef float f32x4 __attribute__((ext_vector_type(4)));

__device__ __forceinline__ unsigned short f2bf(float x) {
    union { float f; unsigned u; } v; v.f = x;
    unsigned r = v.u + 0x7FFFu + ((v.u >> 16) & 1u);
    return (unsigned short)(r >> 16);
}
__device__ __forceinline__ unsigned pack_bf2(float a, float b) {
    return (unsigned)f2bf(a) | ((unsigned)f2bf(b) << 16);
}
__device__ __forceinline__ float bf_lo(unsigned v) {
    union { unsigned u; float f; } w; w.u = (v & 0xFFFFu) << 16; return w.f;
}
__device__ __forceinline__ float bf_hi(unsigned v) {
    union { unsigned u; float f; } w; w.u = v & 0xFFFF0000u; return w.f;
}

// ---------------- CSR build ----------------
__global__ void k_count(const int* __restrict__ dst, int* __restrict__ deg,
                        float* __restrict__ dsum, int E) {
    int e = blockIdx.x * blockDim.x + threadIdx.x;
    if (e == 0) *dsum = 0.f;
    if (e < E) atomicAdd(&deg[dst[e]], 1);
}

__global__ void k_scan_part(const int* __restrict__ deg, int* __restrict__ part, int n) {
    __shared__ int sm[256];
    int b = blockIdx.x, t = threadIdx.x;
    int base = b * 1024 + t * 4;
    int s = 0;
    #pragma unroll
    for (int j = 0; j < 4; j++) if (base + j < n) s += deg[base + j];
    sm[t] = s;
    __syncthreads();
    for (int off = 128; off > 0; off >>= 1) {
        if (t < off) sm[t] += sm[t + off];
        __syncthreads();
    }
    if (t == 0) part[b] = sm[0];
}

__global__ void k_scan_top(const int* __restrict__ part, int* __restrict__ offs,
                           int* __restrict__ row_ptr, int nb, int n) {
    if (threadIdx.x == 0) {
        int acc = 0;
        for (int i = 0; i < nb; i++) { offs[i] = acc; acc += part[i]; }
        row_ptr[n] = acc;
    }
}

__global__ void k_scan_apply(const int* __restrict__ deg, const int* __restrict__ offs,
                             int* __restrict__ row_ptr, int* __restrict__ cursor, int n) {
    __shared__ int sm[256];
    int b = blockIdx.x, t = threadIdx.x;
    int base = b * 1024 + t * 4;
    int v[4]; int s = 0;
    #pragma unroll
    for (int j = 0; j < 4; j++) { v[j] = (base + j < n) ? deg[base + j] : 0; s += v[j]; }
    sm[t] = s;
    __syncthreads();
    for (int off = 1; off < 256; off <<= 1) {
        int y = (t >= off) ? sm[t - off] : 0;
        __syncthreads();
        sm[t] += y;
        __syncthreads();
    }
    int run = offs[b] + sm[t] - s;
    #pragma unroll
    for (int j = 0; j < 4; j++) {
        if (base + j < n) { row_ptr[base + j] = run; cursor[base + j] = run; run += v[j]; }
    }
}

__global__ void k_fill(const int* __restrict__ src, const int* __restrict__ dst,
                       int* __restrict__ cursor, int* __restrict__ csr_src, int E) {
    int e = blockIdx.x * blockDim.x + threadIdx.x;
    if (e < E) {
        int d = dst[e];
        int pos = atomicAdd(&cursor[d], 1);
        csr_src[pos] = src[e];
    }
}

// ---------------- degree scalars ----------------
__global__ void k_delta(const int* __restrict__ deg, float* __restrict__ dsum, int n) {
    int i = blockIdx.x * blockDim.x + threadIdx.x;
    float v = (i < n) ? log1pf((float)deg[i]) : 0.f;
    #pragma unroll
    for (int off = 32; off > 0; off >>= 1) v += __shfl_down(v, off);
    if ((threadIdx.x & 63) == 0) atomicAdd(dsum, v);
}

__global__ void k_scalars(const int* __restrict__ deg, const float* __restrict__ dsum,
                          float* __restrict__ inv_d, float* __restrict__ amp,
                          float* __restrict__ att, int n) {
    int i = blockIdx.x * blockDim.x + threadIdx.x;
    if (i >= n) return;
    float delta = *dsum / (float)n;
    float d = fmaxf((float)deg[i], 1.f);
    float ld = log1pf(d);
    inv_d[i] = 1.f / d;
    amp[i] = ld / delta;
    att[i] = delta / ld;
}

// ---------------- node embedding (fp32 h + bf16 mirror) ----------------
__global__ void k_emb(const float* __restrict__ x, const float* __restrict__ W,
                      const float* __restrict__ b, float* __restrict__ h,
                      unsigned* __restrict__ hb2, int total2) {
    int i = blockIdx.x * blockDim.x + threadIdx.x;
    if (i >= total2) return;
    int node = i >> 6, c = (i & 63) * 2;
    float x0 = x[node * 3 + 0], x1 = x[node * 3 + 1], x2 = x[node * 3 + 2];
    float v0 = x0 * W[c] + x1 * W[DD + c] + x2 * W[2 * DD + c] + b[c];
    float v1 = x0 * W[c + 1] + x1 * W[DD + c + 1] + x2 * W[2 * DD + c + 1] + b[c + 1];
    ((float2*)h)[i] = make_float2(v0, v1);
    hb2[i] = pack_bf2(v0, v1);
}

// ---------------- weight convert: conv_W [L,1536,128] f32 -> Bt [L][3][128][512] bf16 ----
__global__ void k_wconv(const float* __restrict__ W, unsigned short* __restrict__ Bt, int total) {
    int o = blockIdx.x * blockDim.x + threadIdx.x;
    if (o >= total) return;
    int l = o / 196608;
    int r = o % 196608;
    int j = r >> 16;
    int r2 = r & 65535;
    int n = r2 >> 9;
    int k = r2 & 511;
    Bt[o] = f2bf(W[(size_t)l * 196608 + (size_t)(j * 512 + k) * 128 + n]);
}

// ---------------- PNA aggregation (4 nodes/block, wave per node) ----------------
// writes A_t transposed: A_t[kchunk][NPAD nodes][8 shorts], kchunk = k/8,
// k = sec*128 + channel; sections: 0 mean, 1 min, 2 max, 3 std.
__global__ void k_agg(const unsigned* __restrict__ hb2, const int* __restrict__ row_ptr,
                      const int* __restrict__ csr_src, const float* __restrict__ inv_d,
                      unsigned* __restrict__ atw, float* __restrict__ bn_zero) {
    int tid = threadIdx.x;
    if (blockIdx.x == 0) bn_zero[tid] = 0.f;   // zero bn_sum[128]+bn_sq[128] for next gemm
    int node = blockIdx.x * 4 + (tid >> 6);
    int t = tid & 63;
    int beg = row_ptr[node], end = row_ptr[node + 1];
    float s1a = 0.f, s1b = 0.f, s2a = 0.f, s2b = 0.f;
    float mna = INFINITY, mnb = INFINITY, mxa = -INFINITY, mxb = -INFINITY;
    int e = beg;
    for (; e + 1 < end; e += 2) {
        int sa = csr_src[e], sb = csr_src[e + 1];
        unsigned va = hb2[(size_t)sa * 64 + t];
        unsigned vb = hb2[(size_t)sb * 64 + t];
        float a0 = bf_lo(va), b0 = bf_hi(va);
        float a1 = bf_lo(vb), b1 = bf_hi(vb);
        s1a += a0 + a1; s2a += a0 * a0 + a1 * a1;
        mna = fminf(mna, fminf(a0, a1)); mxa = fmaxf(mxa, fmaxf(a0, a1));
        s1b += b0 + b1; s2b += b0 * b0 + b1 * b1;
        mnb = fminf(mnb, fminf(b0, b1)); mxb = fmaxf(mxb, fmaxf(b0, b1));
    }
    if (e < end) {
        int sa = csr_src[e];
        unsigned va = hb2[(size_t)sa * 64 + t];
        float a0 = bf_lo(va), b0 = bf_hi(va);
        s1a += a0; s2a += a0 * a0; mna = fminf(mna, a0); mxa = fmaxf(mxa, a0);
        s1b += b0; s2b += b0 * b0; mnb = fminf(mnb, b0); mxb = fmaxf(mxb, b0);
    }
    float id = inv_d[node];
    float meana = s1a * id, meanb = s1b * id;
    float sda = sqrtf(fmaxf(s2a * id - meana * meana, 0.f) + EPSF);
    float sdb = sqrtf(fmaxf(s2b * id - meanb * meanb, 0.f) + EPSF);
    if (beg == end) { mna = 0.f; mxa = 0.f; mnb = 0.f; mxb = 0.f; }
    // element pair (k=2t, 2t+1) of section sec -> chunk sec*16 + t/4, off t%4
    int cbase = t >> 2, coff = t & 3;
    size_t nn4 = (size_t)NPAD * 4;
    atw[(size_t)(0 * 16 + cbase) * nn4 + (size_t)node * 4 + coff] = pack_bf2(meana, meanb);
    atw[(size_t)(1 * 16 + cbase) * nn4 + (size_t)node * 4 + coff] = pack_bf2(mna, mnb);
    atw[(size_t)(2 * 16 + cbase) * nn4 + (size_t)node * 4 + coff] = pack_bf2(mxa, mxb);
    atw[(size_t)(3 * 16 + cbase) * nn4 + (size_t)node * 4 + coff] = pack_bf2(sda, sdb);
}

// ---------------- MFMA GEMM v7: k-major A direct loads + LDS-resident B ----------------
// A_t[kchunk][NPAD][8] bf16 (k-major: fragment lane axis IS the contiguous axis ->
// coalesced 256B per quad-group, no LDS, no barrier for A).
// B staged into LDS once per 256-k half (96 rows x 264-short padded stride ->
// 2-way bank aliasing = free; 50.7 KB -> 2 blocks/CU).
// Block: 256 thr (4 waves), 32 cols (c0 = blockIdx.y*32), 2 row-tiles of 256
// rows (t0 = bx, bx+98); wave w owns rows [t0*256+64w, +64).
// Barriers: 2 per K-half-stage = 8 per tile-loop total (vs 32/block in v5).
__global__ __launch_bounds__(256, 2) void k_gemm_mfma(
    const unsigned short* __restrict__ At, const unsigned short* __restrict__ Bt,
    const float* __restrict__ bias, const float* __restrict__ amp,
    const float* __restrict__ att, float* __restrict__ outp,
    float* __restrict__ bn_sum, float* __restrict__ bn_sq, int n) {
    __shared__ unsigned short Bs[96 * 264];
    int tid = threadIdx.x;
    int w = tid >> 6, lane = tid & 63;
    int quad = lane >> 4, l16 = lane & 15;
    int c0 = blockIdx.y * 32;

    int b_off[2][3];
    #pragma unroll
    for (int ct = 0; ct < 2; ct++)
        #pragma unroll
        for (int j = 0; j < 3; j++)
            b_off[ct][j] = (j * 32 + ct * 16 + l16) * 264 + quad * 8;

    const size_t STEP = (size_t)4 * NPAD * 8;   // advance 4 kchunks

    for (int t0 = blockIdx.x; t0 < 196; t0 += 98) {
        int base = t0 * 256 + w * 64;
        f32x4 acc[4][2][3];
        #pragma unroll
        for (int rt = 0; rt < 4; rt++)
            #pragma unroll
            for (int ct = 0; ct < 2; ct++)
                #pragma unroll
                for (int j = 0; j < 3; j++) acc[rt][ct][j] = (f32x4)(0.f);

        for (int kh = 0; kh < 2; kh++) {
            __syncthreads();   // previous half's LDS reads complete
            // stage B half: 96 rows x 32 chunks = 3072 chunks, 12/thread
            #pragma unroll
            for (int i = 0; i < 12; i++) {
                int c = i * 256 + tid;
                int row = c >> 5, kcl = c & 31;
                int j = row >> 5, cc = row & 31;
                uint4 v = *(const uint4*)(Bt + (size_t)((j << 7) + c0 + cc) * 512
                                          + kh * 256 + kcl * 8);
                *(uint4*)&Bs[row * 264 + kcl * 8] = v;
            }
            __syncthreads();

            // A pointers for this K-half, prefetch first fragment set
            const unsigned short* pA[4];
            bf16x8 afn[4];
            #pragma unroll
            for (int rt = 0; rt < 4; rt++) {
                pA[rt] = At + ((size_t)(kh * 32 + quad) * NPAD
                               + base + rt * 16 + l16) * 8;
                afn[rt] = *(const bf16x8*)pA[rt];
            }
            #pragma unroll 1
            for (int it = 0; it < 8; it++) {
                bf16x8 af[4];
                #pragma unroll
                for (int rt = 0; rt < 4; rt++) {
                    af[rt] = afn[rt];
                    pA[rt] += STEP;
                    afn[rt] = *(const bf16x8*)pA[rt];  // last iter reads pad chunks (allocated)
                }
                #pragma unroll
                for (int ct = 0; ct < 2; ct++) {
                    #pragma unroll
                    for (int j = 0; j < 3; j++) {
                        bf16x8 bf = *(const bf16x8*)&Bs[b_off[ct][j] + it * 32];
                        #pragma unroll
                        for (int rt = 0; rt < 4; rt++)
                            acc[rt][ct][j] = __builtin_amdgcn_mfma_f32_16x16x32_bf16(
                                af[rt], bf, acc[rt][ct][j], 0, 0, 0);
                    }
                }
            }
        }

        // epilogue: combine j via amp/att, bias, write, BN partials
        float psum[2] = {0.f, 0.f}, psq[2] = {0.f, 0.f};
        #pragma unroll
        for (int rt = 0; rt < 4; rt++) {
            #pragma unroll
            for (int reg = 0; reg < 4; reg++) {
                int row = base + rt * 16 + quad * 4 + reg;
                if (row < n) {
                    float am = amp[row], at = att[row];
                    #pragma unroll
                    for (int ct = 0; ct < 2; ct++) {
                        int col = c0 + ct * 16 + l16;
                        float v = acc[rt][ct][0][reg] + am * acc[rt][ct][1][reg]
                                + at * acc[rt][ct][2][reg] + bias[col];
                        outp[(size_t)row * DD + col] = v;
                        psum[ct] += v;
                        psq[ct] += v * v;
                    }
                }
            }
        }
        #pragma unroll
        for (int ct = 0; ct < 2; ct++) {
            psum[ct] += __shfl_xor(psum[ct], 16, 64);
            psum[ct] += __shfl_xor(psum[ct], 32, 64);
            psq[ct]  += __shfl_xor(psq[ct], 16, 64);
            psq[ct]  += __shfl_xor(psq[ct], 32, 64);
        }
        if (quad == 0) {
            #pragma unroll
            for (int ct = 0; ct < 2; ct++) {
                int col = c0 + ct * 16 + l16;
                atomicAdd(&bn_sum[col], psum[ct]);
                atomicAdd(&bn_sq[col], psq[ct]);
            }
        }
    }
}

// ---------------- BN stats+apply+relu+residual (fused; updates h fp32 + bf16 mirror) ----
__global__ void k_bnapply(const float* __restrict__ outp, const float* __restrict__ bn_sum,
                          const float* __restrict__ bn_sq, const float* __restrict__ gamma,
                          const float* __restrict__ beta, float* __restrict__ h,
                          unsigned* __restrict__ hb2, int total4) {
    int i = blockIdx.x * blockDim.x + threadIdx.x;
    if (i >= total4) return;
    int c = (i & 31) * 4;
    const float invn = 1.f / (float)NN;
    float4 o = ((const float4*)outp)[i];
    float4 hh = ((float4*)h)[i];
    float oo[4] = {o.x, o.y, o.z, o.w};
    float hs[4] = {hh.x, hh.y, hh.z, hh.w};
    #pragma unroll
    for (int j = 0; j < 4; j++) {
        float mu = bn_sum[c + j] * invn;
        float var = bn_sq[c + j] * invn - mu * mu;
        float sc = rsqrtf(var + EPSF) * gamma[c + j];
        float sh = beta[c + j] - mu * sc;
        hs[j] += fmaxf(oo[j] * sc + sh, 0.f);
    }
    ((float4*)h)[i] = make_float4(hs[0], hs[1], hs[2], hs[3]);
    hb2[i * 2]     = pack_bf2(hs[0], hs[1]);
    hb2[i * 2 + 1] = pack_bf2(hs[2], hs[3]);
}

// ---------------- pool + MLP ----------------
__global__ void k_pool_mlp(const float* __restrict__ h, const int* __restrict__ batch,
                           const float* __restrict__ W1, const float* __restrict__ b1,
                           const float* __restrict__ W2, const float* __restrict__ b2,
                           const float* __restrict__ W3, const float* __restrict__ b3,
                           float* __restrict__ out, int n) {
    __shared__ float gvec[128];
    __shared__ float h1[64];
    __shared__ float h2[32];
    __shared__ int srange[2];
    int g = blockIdx.x;
    int t = threadIdx.x;
    if (t < 2) {
        int target = g + t;
        int lo = 0, hi = n;
        while (lo < hi) {
            int mid = (lo + hi) >> 1;
            if (batch[mid] < target) lo = mid + 1; else hi = mid;
        }
        srange[t] = lo;
    }
    __syncthreads();
    int s = srange[0], e = srange[1];
    float acc = 0.f;
    for (int i = s; i < e; i++) acc += h[(size_t)i * DD + t];
    float cnt = fmaxf((float)(e - s), 1.f);
    gvec[t] = acc / cnt;
    __syncthreads();
    if (t < 64) {
        float a = b1[t];
        for (int k = 0; k < 128; k++) a += gvec[k] * W1[k * 64 + t];
        h1[t] = fmaxf(a, 0.f);
    }
    __syncthreads();
    if (t < 32) {
        float a = b2[t];
        for (int k = 0; k < 64; k++) a += h1[k] * W2[k * 32 + t];
        h2[t] = fmaxf(a, 0.f);
    }
    __syncthreads();
    if (t < 10) {
        float a = b3[t];
        for (int k = 0; k < 32; k++) a += h2[k] * W3[k * 10 + t];
        out[g * NT + t] = a;
    }
}

extern "C" void kernel_launch(void* const* d_in, const int* in_sizes, int n_in,
                              void* d_out, int out_size, void* d_ws, size_t ws_size,
                              hipStream_t stream) {
    const float* x      = (const float*)d_in[0];
    const int*   eidx   = (const int*)d_in[1];
    const int*   batch  = (const int*)d_in[2];
    const float* emb_W  = (const float*)d_in[3];
    const float* emb_b  = (const float*)d_in[4];
    const float* conv_W = (const float*)d_in[5];
    const float* conv_b = (const float*)d_in[6];
    const float* bn_g   = (const float*)d_in[7];
    const float* bn_b   = (const float*)d_in[8];
    const float* W1 = (const float*)d_in[9];
    const float* b1 = (const float*)d_in[10];
    const float* W2 = (const float*)d_in[11];
    const float* b2 = (const float*)d_in[12];
    const float* W3 = (const float*)d_in[13];
    const float* b3 = (const float*)d_in[14];
    float* out = (float*)d_out;

    const int* src = eidx;
    const int* dst = eidx + NE;

    char* p = (char*)d_ws;
    auto carve = [&](size_t bytes) {
        void* r = (void*)p;
        p += (bytes + 255) & ~(size_t)255;
        return r;
    };
    int* deg      = (int*)carve(NN * 4);
    int* row_ptr  = (int*)carve((NN + 1) * 4);
    int* cursor   = (int*)carve(NN * 4);
    int* csr_src  = (int*)carve(NE * 4);
    int* part     = (int*)carve(64 * 4);
    int* offs     = (int*)carve(64 * 4);
    float* inv_d  = (float*)carve(NN * 4);
    float* amp    = (float*)carve(NN * 4);
    float* att    = (float*)carve(NN * 4);
    float* dsum   = (float*)carve(4);
    float* bn_sum = (float*)carve(DD * 4);
    float* bn_sq  = (float*)carve(DD * 4);
    float* h      = (float*)carve((size_t)NN * DD * 4);
    unsigned* hb2 = (unsigned*)carve((size_t)NN * 64 * 4);
    unsigned* At  = (unsigned*)carve((size_t)68 * NPAD * 16);   // 64 kchunks + 4 prefetch pad
    float* outp   = (float*)carve((size_t)NN * DD * 4);
    unsigned short* Bt = (unsigned short*)carve((size_t)NL * 3 * 128 * 512 * 2);

    hipMemsetAsync(deg, 0, NN * 4, stream);

    const int NSB = (NN + 1023) / 1024;   // 49 scan blocks
    k_count<<<(NE + 255) / 256, 256, 0, stream>>>(dst, deg, dsum, NE);
    k_scan_part<<<NSB, 256, 0, stream>>>(deg, part, NN);
    k_scan_top<<<1, 64, 0, stream>>>(part, offs, row_ptr, NSB, NN);
    k_scan_apply<<<NSB, 256, 0, stream>>>(deg, offs, row_ptr, cursor, NN);
    k_fill<<<(NE + 255) / 256, 256, 0, stream>>>(src, dst, cursor, csr_src, NE);
    k_delta<<<(NN + 255) / 256, 256, 0, stream>>>(deg, dsum, NN);
    k_scalars<<<(NN + 255) / 256, 256, 0, stream>>>(deg, dsum, inv_d, amp, att, NN);
    k_emb<<<(NN * 64 + 255) / 256, 256, 0, stream>>>(x, emb_W, emb_b, h, hb2, NN * 64);
    k_wconv<<<(NL * 196608 + 255) / 256, 256, 0, stream>>>(conv_W, Bt, NL * 196608);

    dim3 gemm_grid(98, 4);   // 392 blocks, 2/CU (LDS 50.7 KB)
    for (int l = 0; l < NL; l++) {
        k_agg<<<(NN + 3) / 4, 256, 0, stream>>>(hb2, row_ptr, csr_src, inv_d, At, bn_sum);
        k_gemm_mfma<<<gemm_grid, 256, 0, stream>>>(
            (const unsigned short*)At, Bt + (size_t)l * 3 * 128 * 512,
            conv_b + l * DD, amp, att, outp, bn_sum, bn_sq, NN);
        k_bnapply<<<(NN * 32 + 255) / 256, 256, 0, stream>>>(
            outp, bn_sum, bn_sq, bn_g + l * DD, bn_b + l * DD, h, hb2, NN * 32);
    }

    k_pool_mlp<<<NG, 128, 0, stream>>>(h, batch, W1, b1, W2, b2, W3, b3, out, NN);
}